// Round 1
// baseline (2038.802 us; speedup 1.0000x reference)
//
#include <hip/hip_runtime.h>
#include <cmath>

#define B 8
#define DIM 1024
#define T 2048
#define K 8
#define CS 512
#define CHUNK 128
#define EPS 1e-10f

// Kernel 1: per (b,k,t) column — compute 512 logits (+gumbel), argmax,
// scatter codebook row to output, histogram the chosen index.
// X column cached in 128 VGPRs; W rows are wave-uniform -> scalar loads.
__global__ __launch_bounds__(256, 2) void gumbel_argmax_kernel(
    const float* __restrict__ x,          // [B, DIM, T]
    const float* __restrict__ proj_w,     // [K, CS, CHUNK]
    const float* __restrict__ proj_b,     // [K, CS]
    const float* __restrict__ codebooks,  // [K, CS, CHUNK]
    const float* __restrict__ noise,      // [B, K, CS, T]
    float* __restrict__ out,              // [B, DIM, T] (+ K perplexities later)
    unsigned int* __restrict__ counts)    // [K, CS]
{
    const int gid = blockIdx.x * blockDim.x + threadIdx.x;  // over B*K*T
    const int t  = gid % T;
    const int bk = gid / T;
    const int k  = bk % K;
    const int b  = bk / K;

    // load this thread's X column (CHUNK values, stride T) into registers
    const float* xcol = x + ((size_t)b * DIM + (size_t)k * CHUNK) * T + t;
    float xr[CHUNK];
#pragma unroll
    for (int c = 0; c < CHUNK; ++c) xr[c] = xcol[(size_t)c * T];

    const float* wbase = proj_w + (size_t)k * CS * CHUNK;   // wave-uniform
    const float* bbase = proj_b + (size_t)k * CS;           // wave-uniform
    const float* ubase = noise + ((size_t)bk * CS) * T + t; // coalesced in t

    float best = -INFINITY;
    int besto = 0;

    for (int o = 0; o < CS; ++o) {
        // gumbel noise from uniform sample
        const float u = ubase[(size_t)o * T];
        const float g = -logf(-logf(u + EPS) + EPS);
        float acc = bbase[o] + g;
        const float* wr = wbase + o * CHUNK;  // uniform across lanes -> s_load
#pragma unroll
        for (int c = 0; c < CHUNK; ++c) acc = fmaf(wr[c], xr[c], acc);
        if (acc > best) { best = acc; besto = o; }  // strict > keeps first max
    }

    atomicAdd(&counts[k * CS + besto], 1u);

    // gather chosen codebook row, scatter to output column (coalesced in t)
    const float* crow = codebooks + ((size_t)k * CS + besto) * CHUNK;
    float* ocol = out + ((size_t)b * DIM + (size_t)k * CHUNK) * T + t;
#pragma unroll
    for (int c = 0; c < CHUNK; ++c) ocol[(size_t)c * T] = crow[c];
}

// Kernel 2: perplexity per codebook from the histogram.
// 8 waves, wave k handles codebook k; shuffle-reduce over 512 bins.
__global__ void perplexity_kernel(const unsigned int* __restrict__ counts,
                                  float* __restrict__ out)
{
    const int k = threadIdx.x >> 6;
    const int lane = threadIdx.x & 63;
    float sum = 0.0f;
    const float inv_bt = 1.0f / (float)(B * T);
#pragma unroll
    for (int i = lane; i < CS; i += 64) {
        const float avg = (float)counts[k * CS + i] * inv_bt;
        sum += -avg * logf(avg + 1e-8f);   // avg==0 contributes exact 0
    }
#pragma unroll
    for (int off = 32; off > 0; off >>= 1) sum += __shfl_down(sum, off, 64);
    if (lane == 0) out[(size_t)B * DIM * T + k] = expf(sum);
}

extern "C" void kernel_launch(void* const* d_in, const int* in_sizes, int n_in,
                              void* d_out, int out_size, void* d_ws, size_t ws_size,
                              hipStream_t stream) {
    const float* x         = (const float*)d_in[0];
    const float* proj_w    = (const float*)d_in[1];
    const float* proj_b    = (const float*)d_in[2];
    const float* codebooks = (const float*)d_in[3];
    const float* noise     = (const float*)d_in[4];
    float* out             = (float*)d_out;
    unsigned int* counts   = (unsigned int*)d_ws;

    // ws is poisoned 0xAA before every timed launch -> zero the histogram
    hipMemsetAsync(counts, 0, (size_t)K * CS * sizeof(unsigned int), stream);

    const int total = B * K * T;  // 131072 threads, one per (b,k,t)
    gumbel_argmax_kernel<<<total / 256, 256, 0, stream>>>(
        x, proj_w, proj_b, codebooks, noise, out, counts);

    perplexity_kernel<<<1, 512, 0, stream>>>(counts, out);
}

// Round 2
// 866.166 us; speedup vs baseline: 2.3538x; 2.3538x over previous
//
#include <hip/hip_runtime.h>
#include <cmath>

#define B 8
#define DIM 1024
#define T 2048
#define K 8
#define CS 512
#define CHUNK 128
#define TT 64              // t-columns per block
#define OPW 128            // o's per wave (4 waves x 128 = CS)
#define OG 16              // o's per register-tile group
#define NG (OPW / OG)      // 8 groups per wave
#define EPS 1e-10f

// Block = (b,k) x 64-wide t-tile. X tile staged in LDS; W read via
// wave-uniform scalar loads; 16-o register accumulator tile per lane;
// gumbel+argmax fused; coalesced codebook scatter at the end.
__global__ __launch_bounds__(256, 4) void gumbel_fused_kernel(
    const float* __restrict__ x,          // [B, K, CHUNK, T]
    const float* __restrict__ proj_w,     // [K, CS, CHUNK]
    const float* __restrict__ proj_b,     // [K, CS]
    const float* __restrict__ codebooks,  // [K, CS, CHUNK]
    const float* __restrict__ noise,      // [B, K, CS, T]
    float* __restrict__ out,              // [B, K, CHUNK, T] then K perplexities
    unsigned int* __restrict__ counts)    // [K, CS]
{
    __shared__ float Xs[CHUNK * TT];      // 32 KB
    __shared__ float redv[4][TT];         // 1 KB
    __shared__ int   redi[4][TT];         // 1 KB

    const int tid = threadIdx.x;
    const int nt = T / TT;                // 32
    const int t0 = (blockIdx.x % nt) * TT;
    const int bk = blockIdx.x / nt;       // b*K + k
    const int k = bk % K;

    // ---- stage X tile [CHUNK][TT] into LDS (coalesced float4) ----
    {
        const float* xb = x + (size_t)bk * CHUNK * T + t0;
        const int nv = CHUNK * TT / 4;    // 2048 float4
        for (int i = tid; i < nv; i += 256) {
            const int row = i >> 4;       // TT/4 = 16 float4 per row
            const int c4 = (i & 15) << 2;
            const float4 v = *(const float4*)(xb + (size_t)row * T + c4);
            *(float4*)(&Xs[row * TT + c4]) = v;
        }
    }
    __syncthreads();

    // wave index forced wave-uniform -> scalar W addressing
    const int w = __builtin_amdgcn_readfirstlane(tid >> 6);
    const int lane = tid & 63;            // owns t = t0 + lane

    const float* wb = proj_w + ((size_t)k * CS + w * OPW) * CHUNK;
    const float* bb = proj_b + (size_t)k * CS + w * OPW;
    const float* nb = noise + ((size_t)bk * CS + w * OPW) * T + t0 + lane;

    float bv = -INFINITY;
    int bi = 0;

    for (int og = 0; og < NG; ++og) {
        float acc[OG];
#pragma unroll
        for (int oo = 0; oo < OG; ++oo) acc[oo] = 0.f;

        const float* wrow = wb + (size_t)(og * OG) * CHUNK;
        for (int cb = 0; cb < CHUNK; cb += 4) {
            float xv[4];
#pragma unroll
            for (int j = 0; j < 4; ++j) xv[j] = Xs[(cb + j) * TT + lane];
#pragma unroll
            for (int oo = 0; oo < OG; ++oo) {
                const float* wr = wrow + oo * CHUNK + cb;  // wave-uniform
#pragma unroll
                for (int j = 0; j < 4; ++j)
                    acc[oo] = fmaf(wr[j], xv[j], acc[oo]);
            }
        }

        // epilogue: bias + gumbel, running argmax (ascending o, strict >)
#pragma unroll
        for (int oo = 0; oo < OG; ++oo) {
            const int o = og * OG + oo;
            const float u = nb[(size_t)o * T];
            const float g = -logf(-logf(u + EPS) + EPS);
            const float logit = acc[oo] + bb[o] + g;
            if (logit > bv) { bv = logit; bi = w * OPW + o; }
        }
    }

    redv[w][lane] = bv;
    redi[w][lane] = bi;
    __syncthreads();

    // cross-wave argmax; ascending wave order keeps lowest-o on ties
    if (tid < TT) {
        float best = redv[0][tid];
        int besti = redi[0][tid];
#pragma unroll
        for (int ww = 1; ww < 4; ++ww) {
            if (redv[ww][tid] > best) { best = redv[ww][tid]; besti = redi[ww][tid]; }
        }
        redi[0][tid] = besti;
        atomicAdd(&counts[k * CS + besti], 1u);
    }
    __syncthreads();

    // ---- scatter codebook rows to output tile (stores coalesced in t) ----
    {
        const int t = tid & (TT - 1);
        const int cq = tid >> 6;          // 4 groups of 32 c's
        const int row = redi[0][t];
        const float* crow = codebooks + ((size_t)k * CS + row) * CHUNK + cq * 32;
        float* ob = out + (size_t)bk * CHUNK * T + t0 + t;
#pragma unroll
        for (int i = 0; i < 8; ++i) {
            const float4 v = *(const float4*)(crow + i * 4);
            const int c = cq * 32 + i * 4;
            ob[(size_t)(c + 0) * T] = v.x;
            ob[(size_t)(c + 1) * T] = v.y;
            ob[(size_t)(c + 2) * T] = v.z;
            ob[(size_t)(c + 3) * T] = v.w;
        }
    }
}

// Perplexity per codebook from the histogram. Wave k handles codebook k.
__global__ void perplexity_kernel(const unsigned int* __restrict__ counts,
                                  float* __restrict__ out)
{
    const int k = threadIdx.x >> 6;
    const int lane = threadIdx.x & 63;
    float sum = 0.0f;
    const float inv_bt = 1.0f / (float)(B * T);
#pragma unroll
    for (int i = lane; i < CS; i += 64) {
        const float avg = (float)counts[k * CS + i] * inv_bt;
        sum += -avg * logf(avg + 1e-8f);   // avg==0 contributes exact 0
    }
#pragma unroll
    for (int off = 32; off > 0; off >>= 1) sum += __shfl_down(sum, off, 64);
    if (lane == 0) out[(size_t)B * DIM * T + k] = expf(sum);
}

extern "C" void kernel_launch(void* const* d_in, const int* in_sizes, int n_in,
                              void* d_out, int out_size, void* d_ws, size_t ws_size,
                              hipStream_t stream) {
    const float* x         = (const float*)d_in[0];
    const float* proj_w    = (const float*)d_in[1];
    const float* proj_b    = (const float*)d_in[2];
    const float* codebooks = (const float*)d_in[3];
    const float* noise     = (const float*)d_in[4];
    float* out             = (float*)d_out;
    unsigned int* counts   = (unsigned int*)d_ws;

    // d_ws is re-poisoned before every timed launch -> zero the histogram
    hipMemsetAsync(counts, 0, (size_t)K * CS * sizeof(unsigned int), stream);

    const int nblocks = B * K * (T / TT);   // 2048
    gumbel_fused_kernel<<<nblocks, 256, 0, stream>>>(
        x, proj_w, proj_b, codebooks, noise, out, counts);

    perplexity_kernel<<<1, 512, 0, stream>>>(counts, out);
}